// Round 9
// baseline (165.485 us; speedup 1.0000x reference)
//
#include <hip/hip_runtime.h>
#include <hip/hip_bf16.h>
#include <stdint.h>

#define B_N 4
#define NQ 1024
#define NKV 2048
#define DI 1024
#define H 16
#define DH 64

using bf16 = __bf16;
typedef bf16 bf16x8 __attribute__((ext_vector_type(8)));
typedef bf16 bf16x4 __attribute__((ext_vector_type(4)));
typedef float f32x4 __attribute__((ext_vector_type(4)));

typedef const __attribute__((address_space(1))) void* gptr_t;
typedef __attribute__((address_space(3))) void* sptr_t;

// ---------------- fused f32 -> bf16 convert of all three weights ----------------
__global__ __launch_bounds__(256) void cvt_all(const float* __restrict__ Wq,
    const float* __restrict__ Wkv, const float* __restrict__ Wproj,
    bf16* __restrict__ oq, bf16* __restrict__ okv, bf16* __restrict__ op) {
  int i = blockIdx.x * 256 + threadIdx.x;
  const float* src; bf16* dst; int j;
  if (i < 262144)      { src = Wq;    dst = oq;  j = i; }
  else if (i < 786432) { src = Wkv;   dst = okv; j = i - 262144; }
  else                 { src = Wproj; dst = op;  j = i - 786432; }
  float4 v = reinterpret_cast<const float4*>(src)[j];
  bf16x4 o;
  o[0] = (bf16)v.x; o[1] = (bf16)v.y; o[2] = (bf16)v.z; o[3] = (bf16)v.w;
  reinterpret_cast<bf16x4*>(dst)[j] = o;
}

// ---------------- fused LayerNorm (q rows then ctx rows) -> bf16 ----------------
__global__ __launch_bounds__(256) void ln_kernel(const float* __restrict__ q,
    const float* __restrict__ ctx,
    const float* __restrict__ qg, const float* __restrict__ qb,
    const float* __restrict__ cg, const float* __restrict__ cb,
    bf16* __restrict__ qn, bf16* __restrict__ cn) {
  int row = blockIdx.x;
  const float* x; const float* gamma; const float* beta; bf16* out; int r;
  if (row < 4096) { x = q;   gamma = qg; beta = qb; out = qn; r = row; }
  else            { x = ctx; gamma = cg; beta = cb; out = cn; r = row - 4096; }
  int t = threadIdx.x;
  const float4 v = reinterpret_cast<const float4*>(x + (size_t)r * 1024)[t];
  float s = v.x + v.y + v.z + v.w;
  float s2 = v.x*v.x + v.y*v.y + v.z*v.z + v.w*v.w;
#pragma unroll
  for (int m = 1; m < 64; m <<= 1) { s += __shfl_xor(s, m); s2 += __shfl_xor(s2, m); }
  __shared__ float red[8];
  int wid = t >> 6;
  if ((t & 63) == 0) { red[wid] = s; red[wid + 4] = s2; }
  __syncthreads();
  float ts  = red[0] + red[1] + red[2] + red[3];
  float ts2 = red[4] + red[5] + red[6] + red[7];
  float mean = ts * (1.0f / 1024.0f);
  float var  = ts2 * (1.0f / 1024.0f) - mean * mean;
  float rstd = rsqrtf(var + 1e-5f);
  float4 g  = reinterpret_cast<const float4*>(gamma)[t];
  float4 bb = reinterpret_cast<const float4*>(beta)[t];
  bf16x4 o;
  o[0] = (bf16)((v.x - mean) * rstd * g.x + bb.x);
  o[1] = (bf16)((v.y - mean) * rstd * g.y + bb.y);
  o[2] = (bf16)((v.z - mean) * rstd * g.z + bb.z);
  o[3] = (bf16)((v.w - mean) * rstd * g.w + bb.w);
  reinterpret_cast<bf16x4*>(out + (size_t)r * 1024)[t] = o;
}

// ---------------- GEMM body: C[m,n] = sum_k A[m,k]*Bm[n,k]  (K=1024) ----------------
// Tile: 128 x BN, BK=64, 4 waves. LDS XOR-swizzled (slot ^= row&7) with
// pre-swizzled global source (linear LDS dest for global_load_lds) + swizzled read.
// MODE 0: bf16 out, * (0.125*log2e) (qp) | MODE 1: kv split K + V^T-permuted | MODE 2: f32+bias
template<int MODE, int BN>
__device__ __forceinline__ void gemm_body(bf16* lA, bf16* lB,
    const bf16* __restrict__ A, const bf16* __restrict__ Bm,
    void* __restrict__ out0, void* __restrict__ out1,
    const float* __restrict__ bias, int M, int N, int bid) {
  constexpr int K = 1024;
  constexpr int MI = (BN == 128) ? 4 : 2;
  constexpr int NBL = (BN == 128) ? 4 : 2;
  const int nbn = N / BN;
  const int bm = bid / nbn, bn = bid - bm * nbn;
  const int m0 = bm << 7, n0 = bn * BN;
  const int tid = threadIdx.x;
  const int lane = tid & 63, wid = tid >> 6;
  const int rowb = (BN == 128) ? ((wid >> 1) * 64) : (wid * 32);
  const int colb = (BN == 128) ? ((wid & 1) * 64) : 0;
  const int l15 = lane & 15, lg = lane >> 4;

  f32x4 acc[MI][4] = {};

  const bf16* gA[4]; const bf16* gB[NBL];
#pragma unroll
  for (int u = 0; u < 4; ++u) {
    int s = tid + u * 256;
    int row = s >> 3, c8 = (s & 7) ^ (row & 7);
    gA[u] = A + (size_t)(m0 + row) * K + c8 * 8;
  }
#pragma unroll
  for (int u = 0; u < NBL; ++u) {
    int s = tid + u * 256;
    int row = s >> 3, c8 = (s & 7) ^ (row & 7);
    gB[u] = Bm + (size_t)(n0 + row) * K + c8 * 8;
  }

  const int sw = l15 & 7;

  for (int k0 = 0; k0 < K; k0 += 64) {
#pragma unroll
    for (int u = 0; u < 4; ++u)
      __builtin_amdgcn_global_load_lds((gptr_t)(gA[u] + k0), (sptr_t)(lA + (tid + u * 256) * 8), 16, 0, 0);
#pragma unroll
    for (int u = 0; u < NBL; ++u)
      __builtin_amdgcn_global_load_lds((gptr_t)(gB[u] + k0), (sptr_t)(lB + (tid + u * 256) * 8), 16, 0, 0);
    __syncthreads();
#pragma unroll
    for (int ks2 = 0; ks2 < 2; ++ks2) {
      const int soff = ((ks2 * 4 + lg) ^ sw) * 8;
      bf16x8 af[MI], bfr[4];
#pragma unroll
      for (int i = 0; i < MI; ++i)
        af[i]  = *reinterpret_cast<const bf16x8*>(lA + (rowb + i * 16 + l15) * 64 + soff);
#pragma unroll
      for (int j = 0; j < 4; ++j)
        bfr[j] = *reinterpret_cast<const bf16x8*>(lB + (colb + j * 16 + l15) * 64 + soff);
#pragma unroll
      for (int i = 0; i < MI; ++i)
#pragma unroll
        for (int j = 0; j < 4; ++j)
          acc[i][j] = __builtin_amdgcn_mfma_f32_16x16x32_bf16(af[i], bfr[j], acc[i][j], 0, 0, 0);
    }
    __syncthreads();
  }

  const int mB = m0 + rowb + lg * 4;
  const int nB = n0 + colb + l15;
  if constexpr (MODE == 0) {
    bf16* o = reinterpret_cast<bf16*>(out0);
    constexpr float SC = 0.125f * 1.44269504089f;  // DH^-0.5 * log2(e)
#pragma unroll
    for (int i = 0; i < MI; ++i)
#pragma unroll
      for (int j = 0; j < 4; ++j)
#pragma unroll
        for (int r = 0; r < 4; ++r)
          o[(size_t)(mB + i * 16 + r) * N + nB + j * 16] = (bf16)(acc[i][j][r] * SC);
  } else if constexpr (MODE == 2) {
    float* o = reinterpret_cast<float*>(out0);
#pragma unroll
    for (int j = 0; j < 4; ++j) {
      float bj = bias[nB + j * 16];
#pragma unroll
      for (int i = 0; i < MI; ++i)
#pragma unroll
        for (int r = 0; r < 4; ++r)
          o[(size_t)(mB + i * 16 + r) * N + nB + j * 16] = acc[i][j][r] + bj;
    }
  } else {
    if (n0 < 1024) {  // K part: (B,NKV,DI)
      bf16* o = reinterpret_cast<bf16*>(out0);
#pragma unroll
      for (int i = 0; i < MI; ++i)
#pragma unroll
        for (int j = 0; j < 4; ++j)
#pragma unroll
          for (int r = 0; r < 4; ++r)
            o[(size_t)(mB + i * 16 + r) * 1024 + nB + j * 16] = (bf16)acc[i][j][r];
    } else {          // V part: transposed (B,DI,NKV) with in-64 column swizzle
      bf16* o = reinterpret_cast<bf16*>(out1);
#pragma unroll
      for (int i = 0; i < MI; ++i) {
        int m = mB + i * 16;
        int bb_ = m >> 11, kv = m & 2047;
        int u = kv & 63;
        int c = (u & 32) | ((u & 12) << 1) | ((u & 16) >> 2) | (u & 3);
        int col = (kv & ~63) | c;
#pragma unroll
        for (int j = 0; j < 4; ++j) {
          int nv = nB + j * 16 - 1024;
          bf16x4 pk;
          pk[0] = (bf16)acc[i][j][0]; pk[1] = (bf16)acc[i][j][1];
          pk[2] = (bf16)acc[i][j][2]; pk[3] = (bf16)acc[i][j][3];
          *reinterpret_cast<bf16x4*>(o + ((size_t)(bb_ << 10) + nv) * 2048 + col) = pk;
        }
      }
    }
  }
}

template<int MODE, int BN>
__global__ __launch_bounds__(256) void gemm_bt(const bf16* __restrict__ A,
    const bf16* __restrict__ Bm, void* __restrict__ out0, void* __restrict__ out1,
    const float* __restrict__ bias, int M, int N) {
  __shared__ bf16 lA[128 * 64];
  __shared__ bf16 lB[BN * 64];
  const int cpx = gridDim.x >> 3;
  const int bid = (blockIdx.x & 7) * cpx + (blockIdx.x >> 3);
  gemm_body<MODE, BN>(lA, lB, A, Bm, out0, out1, bias, M, N, bid);
}

// Merged qp + kv GEMM: blocks [0,1024) = kv (MODE 1), [1024,1280) = qp (MODE 0, BN=128).
__global__ __launch_bounds__(256) void gemm_fused(
    const bf16* __restrict__ qn, const bf16* __restrict__ Wq, void* __restrict__ qpb,
    const bf16* __restrict__ cn, const bf16* __restrict__ Wkv,
    void* __restrict__ kbuf, void* __restrict__ vT) {
  __shared__ bf16 lA[128 * 64];
  __shared__ bf16 lB[128 * 64];
  if (blockIdx.x < 1024) {
    int rb = blockIdx.x;
    int bid = (rb & 7) * 128 + (rb >> 3);
    gemm_body<1, 128>(lA, lB, cn, Wkv, kbuf, vT, nullptr, 8192, 2048, bid);
  } else {
    int rb = blockIdx.x - 1024;
    int bid = (rb & 7) * 32 + (rb >> 3);
    gemm_body<0, 128>(lA, lB, qn, Wq, qpb, nullptr, nullptr, 4096, 1024, bid);
  }
}

// ---------------- Flash attention v8: 4 waves x 32q, KVBLK=128, LDS-staged K/V ----------------
// S^T = mfma(K, Q): lane holds S[q = lane&15][kv = ni*16 + lg*4 + r] (exp2-domain logits).
// Each wave owns 32 q rows (mi=0,1): halves per-block LDS read redundancy vs 16q/wave.
// Joint running max across the two 16-row groups (exact: corr telescopes for any valid m).
__global__ __launch_bounds__(256) void attn_kernel(const bf16* __restrict__ qp,
    const bf16* __restrict__ kk, const bf16* __restrict__ vTp, bf16* __restrict__ out) {
  __shared__ bf16 smem[32768];   // [K dbuf 2x8192][V dbuf 2x8192]  (64 KB)
  const int pos = blockIdx.x;
  const int idx = pos >> 3;
  const int bh = ((idx >> 3) << 3) | (pos & 7);
  const int qt = idx & 7;
  const int b = bh >> 4, h = bh & 15;
  const int tid = threadIdx.x;              // 0..255
  const int lane = tid & 63, w = tid >> 6;  // 4 waves
  const int l15 = lane & 15, lg = lane >> 4;

  const bf16* Qb = qp + (size_t)(b * NQ + qt * 128 + w * 32) * DI + h * DH;
  const bf16* Kb = kk + (size_t)b * NKV * DI + h * DH;
  const bf16* Vb = vTp + (size_t)(b * DI + h * DH) * NKV;

  // K slots (1024 x 16B): bits [9:7]=ni, [6]=ks, [5:4]=lg, [3:0]=l15
  // V slots (1024 x 16B): bits [9:8]=dt, [7:6]=k2, [5:4]=lg, [3:0]=l15
  const bf16* pK[4]; const bf16* pV[4];
#pragma unroll
  for (int u = 0; u < 4; ++u) {
    int s = tid + u * 256;
    int rK = ((s >> 7) << 4) | (s & 15), cK = ((s >> 4) & 7) * 8;
    int rV = ((s >> 8) << 4) | (s & 15), cV = ((s >> 6) & 3) * 32 + ((s >> 4) & 3) * 8;
    pK[u] = Kb + (size_t)rK * DI + cK;
    pV[u] = Vb + (size_t)rV * NKV + cV;
  }

  auto STAGE = [&](int bufsel, int kv) {
#pragma unroll
    for (int u = 0; u < 4; ++u) {
      __builtin_amdgcn_global_load_lds((gptr_t)(pK[u] + (size_t)kv * DI),
          (sptr_t)(smem + bufsel * 8192 + (tid + u * 256) * 8), 16, 0, 0);
      __builtin_amdgcn_global_load_lds((gptr_t)(pV[u] + kv),
          (sptr_t)(smem + 16384 + bufsel * 8192 + (tid + u * 256) * 8), 16, 0, 0);
    }
  };

  bf16x8 qf[2][2];
#pragma unroll
  for (int mi = 0; mi < 2; ++mi)
#pragma unroll
    for (int ks = 0; ks < 2; ++ks)
      qf[mi][ks] = *reinterpret_cast<const bf16x8*>(Qb + (size_t)(mi * 16 + l15) * DI + ks * 32 + lg * 8);

  f32x4 o[2][4] = {};
  float mrun = -1e30f;
  float lpart0 = 0.0f, lpart1 = 0.0f;

  STAGE(0, 0);
  __syncthreads();
  int cur = 0;

  for (int kv0 = 0; kv0 < NKV; kv0 += 128) {
    const bool notlast = (kv0 + 128 < NKV);
    if (notlast) STAGE(cur ^ 1, kv0 + 128);

    const bf16* Kl = smem + cur * 8192;
    const bf16* Vl = smem + 16384 + cur * 8192;

    // ---- QK^T (swapped operands), two 64-kv groups, two q groups ----
    f32x4 s[2][8] = {};
#pragma unroll
    for (int h2 = 0; h2 < 2; ++h2) {
      bf16x8 kf[4][2];
#pragma unroll
      for (int ni = 0; ni < 4; ++ni)
#pragma unroll
        for (int ks = 0; ks < 2; ++ks)
          kf[ni][ks] = *reinterpret_cast<const bf16x8*>(Kl + (((h2 * 4 + ni) * 2 + ks) * 64 + lane) * 8);
      __builtin_amdgcn_s_setprio(1);
#pragma unroll
      for (int mi = 0; mi < 2; ++mi)
#pragma unroll
        for (int ni = 0; ni < 4; ++ni)
#pragma unroll
          for (int ks = 0; ks < 2; ++ks)
            s[mi][h2 * 4 + ni] = __builtin_amdgcn_mfma_f32_16x16x32_bf16(kf[ni][ks], qf[mi][ks], s[mi][h2 * 4 + ni], 0, 0, 0);
      __builtin_amdgcn_s_setprio(0);
    }

    // ---- softmax: joint max across both q groups (per q = l15; exp2 domain) ----
    f32x4 mv = s[0][0];
#pragma unroll
    for (int i = 1; i < 8; ++i) {
      mv[0] = fmaxf(mv[0], s[0][i][0]); mv[1] = fmaxf(mv[1], s[0][i][1]);
      mv[2] = fmaxf(mv[2], s[0][i][2]); mv[3] = fmaxf(mv[3], s[0][i][3]);
    }
#pragma unroll
    for (int i = 0; i < 8; ++i) {
      mv[0] = fmaxf(mv[0], s[1][i][0]); mv[1] = fmaxf(mv[1], s[1][i][1]);
      mv[2] = fmaxf(mv[2], s[1][i][2]); mv[3] = fmaxf(mv[3], s[1][i][3]);
    }
    float pm = fmaxf(fmaxf(mv[0], mv[1]), fmaxf(mv[2], mv[3]));
    pm = fmaxf(pm, __shfl_xor(pm, 16));
    pm = fmaxf(pm, __shfl_xor(pm, 32));

    const bool noresc = __all(pm <= mrun);
    const float mnew = noresc ? mrun : fmaxf(mrun, pm);

    float rs0, rs1;
    {
      f32x4 sv = {};
#pragma unroll
      for (int i = 0; i < 8; ++i)
#pragma unroll
        for (int r = 0; r < 4; ++r) {
          s[0][i][r] = __builtin_amdgcn_exp2f(s[0][i][r] - mnew);
          sv[r] += s[0][i][r];
        }
      rs0 = (sv[0] + sv[1]) + (sv[2] + sv[3]);
    }
    {
      f32x4 sv = {};
#pragma unroll
      for (int i = 0; i < 8; ++i)
#pragma unroll
        for (int r = 0; r < 4; ++r) {
          s[1][i][r] = __builtin_amdgcn_exp2f(s[1][i][r] - mnew);
          sv[r] += s[1][i][r];
        }
      rs1 = (sv[0] + sv[1]) + (sv[2] + sv[3]);
    }

    if (noresc) {
      lpart0 += rs0; lpart1 += rs1;
    } else {
      float corr = __builtin_amdgcn_exp2f(mrun - mnew);
      lpart0 = lpart0 * corr + rs0;
      lpart1 = lpart1 * corr + rs1;
      mrun = mnew;
      float c0 = __shfl(corr, lg * 4 + 0);
      float c1 = __shfl(corr, lg * 4 + 1);
      float c2 = __shfl(corr, lg * 4 + 2);
      float c3 = __shfl(corr, lg * 4 + 3);
#pragma unroll
      for (int mi = 0; mi < 2; ++mi)
#pragma unroll
        for (int dt = 0; dt < 4; ++dt) {
          o[mi][dt][0] *= c0; o[mi][dt][1] *= c1; o[mi][dt][2] *= c2; o[mi][dt][3] *= c3;
        }
    }

    // ---- pack P (register-only): pa[mi][k2], k2 = h2*2 + k2' ----
    bf16x8 pa[2][4];
#pragma unroll
    for (int mi = 0; mi < 2; ++mi)
#pragma unroll
      for (int h2 = 0; h2 < 2; ++h2)
#pragma unroll
        for (int k2p = 0; k2p < 2; ++k2p)
#pragma unroll
          for (int jj = 0; jj < 4; ++jj) {
            pa[mi][h2 * 2 + k2p][jj]     = (bf16)s[mi][h2 * 4 + k2p * 2 + 0][jj];
            pa[mi][h2 * 2 + k2p][4 + jj] = (bf16)s[mi][h2 * 4 + k2p * 2 + 1][jj];
          }

    // ---- PV: V fragments shared by both q groups ----
    __builtin_amdgcn_s_setprio(1);
#pragma unroll
    for (int k2 = 0; k2 < 4; ++k2) {
      bf16x8 vf[4];
#pragma unroll
      for (int dt = 0; dt < 4; ++dt)
        vf[dt] = *reinterpret_cast<const bf16x8*>(Vl + ((dt * 4 + k2) * 64 + lane) * 8);
#pragma unroll
      for (int mi = 0; mi < 2; ++mi)
#pragma unroll
        for (int dt = 0; dt < 4; ++dt)
          o[mi][dt] = __builtin_amdgcn_mfma_f32_16x16x32_bf16(pa[mi][k2], vf[dt], o[mi][dt], 0, 0, 0);
    }
    __builtin_amdgcn_s_setprio(0);

    if (notlast) __syncthreads();
    cur ^= 1;
  }

  // epilogue: reduce per-lane partials, normalize, store
#pragma unroll
  for (int mi = 0; mi < 2; ++mi) {
    float lsum = (mi == 0) ? lpart0 : lpart1;
    lsum += __shfl_xor(lsum, 16);
    lsum += __shfl_xor(lsum, 32);
    const float inv = 1.0f / lsum;               // valid for q = l15
    const float iv0 = __shfl(inv, lg * 4 + 0);
    const float iv1 = __shfl(inv, lg * 4 + 1);
    const float iv2 = __shfl(inv, lg * 4 + 2);
    const float iv3 = __shfl(inv, lg * 4 + 3);
    bf16* Ob = out + (size_t)(b * NQ + qt * 128 + w * 32 + mi * 16) * DI + h * DH;
#pragma unroll
    for (int dt = 0; dt < 4; ++dt) {
      Ob[(size_t)(lg * 4 + 0) * DI + dt * 16 + l15] = (bf16)(o[mi][dt][0] * iv0);
      Ob[(size_t)(lg * 4 + 1) * DI + dt * 16 + l15] = (bf16)(o[mi][dt][1] * iv1);
      Ob[(size_t)(lg * 4 + 2) * DI + dt * 16 + l15] = (bf16)(o[mi][dt][2] * iv2);
      Ob[(size_t)(lg * 4 + 3) * DI + dt * 16 + l15] = (bf16)(o[mi][dt][3] * iv3);
    }
  }
}

// ---------------- launch ----------------
extern "C" void kernel_launch(void* const* d_in, const int* in_sizes, int n_in,
                              void* d_out, int out_size, void* d_ws, size_t ws_size,
                              hipStream_t stream) {
  const float* q     = (const float*)d_in[0];
  const float* ctx   = (const float*)d_in[1];
  const float* Wq    = (const float*)d_in[2];
  const float* Wkv   = (const float*)d_in[3];
  const float* Wproj = (const float*)d_in[4];
  const float* bproj = (const float*)d_in[5];
  const float* qg    = (const float*)d_in[6];
  const float* qb    = (const float*)d_in[7];
  const float* cg    = (const float*)d_in[8];
  const float* cb    = (const float*)d_in[9];

  char* ws = (char*)d_ws;
  bf16* qn    = (bf16*)(ws);                       // 8 MB  (4096x1024)
  bf16* cn    = (bf16*)(ws + ( 8ull << 20));       // 16 MB (8192x1024)
  bf16* Wq_b  = (bf16*)(ws + (24ull << 20));       // 2 MB
  bf16* Wkv_b = (bf16*)(ws + (26ull << 20));       // 4 MB
  bf16* Wp_b  = (bf16*)(ws + (30ull << 20));       // 2 MB
  bf16* qpb   = (bf16*)(ws + (32ull << 20));       // 8 MB  (4096x1024)
  bf16* kbuf  = (bf16*)(ws + (40ull << 20));       // 16 MB (B,NKV,DI)
  bf16* vT    = (bf16*)(ws + (56ull << 20));       // 16 MB (B,DI,NKV) swizzled
  bf16* aout  = (bf16*)(ws + (72ull << 20));       // 8 MB  (4096x1024)

  cvt_all<<<4096, 256, 0, stream>>>(Wq, Wkv, Wproj, Wq_b, Wkv_b, Wp_b);
  ln_kernel<<<12288, 256, 0, stream>>>(q, ctx, qg, qb, cg, cb, qn, cn);

  gemm_fused<<<1280, 256, 0, stream>>>(qn, Wq_b, qpb, cn, Wkv_b, kbuf, vT);

  attn_kernel<<<512, 256, 0, stream>>>(qpb, kbuf, vT, aout);

  gemm_bt<2, 64><<<512, 256, 0, stream>>>(aout, Wp_b, d_out, nullptr, bproj, 4096, 1024);
}

// Round 10
// 142.509 us; speedup vs baseline: 1.1612x; 1.1612x over previous
//
#include <hip/hip_runtime.h>
#include <hip/hip_bf16.h>
#include <stdint.h>

#define B_N 4
#define NQ 1024
#define NKV 2048
#define DI 1024
#define H 16
#define DH 64

using bf16 = __bf16;
typedef bf16 bf16x8 __attribute__((ext_vector_type(8)));
typedef bf16 bf16x4 __attribute__((ext_vector_type(4)));
typedef float f32x4 __attribute__((ext_vector_type(4)));

typedef const __attribute__((address_space(1))) void* gptr_t;
typedef __attribute__((address_space(3))) void* sptr_t;

// ---------------- fused f32 -> bf16 convert of all three weights ----------------
__global__ __launch_bounds__(256) void cvt_all(const float* __restrict__ Wq,
    const float* __restrict__ Wkv, const float* __restrict__ Wproj,
    bf16* __restrict__ oq, bf16* __restrict__ okv, bf16* __restrict__ op) {
  int i = blockIdx.x * 256 + threadIdx.x;
  const float* src; bf16* dst; int j;
  if (i < 262144)      { src = Wq;    dst = oq;  j = i; }
  else if (i < 786432) { src = Wkv;   dst = okv; j = i - 262144; }
  else                 { src = Wproj; dst = op;  j = i - 786432; }
  float4 v = reinterpret_cast<const float4*>(src)[j];
  bf16x4 o;
  o[0] = (bf16)v.x; o[1] = (bf16)v.y; o[2] = (bf16)v.z; o[3] = (bf16)v.w;
  reinterpret_cast<bf16x4*>(dst)[j] = o;
}

// ---------------- fused LayerNorm (q rows then ctx rows) -> bf16 ----------------
__global__ __launch_bounds__(256) void ln_kernel(const float* __restrict__ q,
    const float* __restrict__ ctx,
    const float* __restrict__ qg, const float* __restrict__ qb,
    const float* __restrict__ cg, const float* __restrict__ cb,
    bf16* __restrict__ qn, bf16* __restrict__ cn) {
  int row = blockIdx.x;
  const float* x; const float* gamma; const float* beta; bf16* out; int r;
  if (row < 4096) { x = q;   gamma = qg; beta = qb; out = qn; r = row; }
  else            { x = ctx; gamma = cg; beta = cb; out = cn; r = row - 4096; }
  int t = threadIdx.x;
  const float4 v = reinterpret_cast<const float4*>(x + (size_t)r * 1024)[t];
  float s = v.x + v.y + v.z + v.w;
  float s2 = v.x*v.x + v.y*v.y + v.z*v.z + v.w*v.w;
#pragma unroll
  for (int m = 1; m < 64; m <<= 1) { s += __shfl_xor(s, m); s2 += __shfl_xor(s2, m); }
  __shared__ float red[8];
  int wid = t >> 6;
  if ((t & 63) == 0) { red[wid] = s; red[wid + 4] = s2; }
  __syncthreads();
  float ts  = red[0] + red[1] + red[2] + red[3];
  float ts2 = red[4] + red[5] + red[6] + red[7];
  float mean = ts * (1.0f / 1024.0f);
  float var  = ts2 * (1.0f / 1024.0f) - mean * mean;
  float rstd = rsqrtf(var + 1e-5f);
  float4 g  = reinterpret_cast<const float4*>(gamma)[t];
  float4 bb = reinterpret_cast<const float4*>(beta)[t];
  bf16x4 o;
  o[0] = (bf16)((v.x - mean) * rstd * g.x + bb.x);
  o[1] = (bf16)((v.y - mean) * rstd * g.y + bb.y);
  o[2] = (bf16)((v.z - mean) * rstd * g.z + bb.z);
  o[3] = (bf16)((v.w - mean) * rstd * g.w + bb.w);
  reinterpret_cast<bf16x4*>(out + (size_t)r * 1024)[t] = o;
}

// ---------------- GEMM body: C[m,n] = sum_k A[m,k]*Bm[n,k]  (K=1024) ----------------
// Tile: 128 x BN, BK=64, 4 waves. LDS XOR-swizzled (slot ^= row&7) with
// pre-swizzled global source (linear LDS dest for global_load_lds) + swizzled read.
// MODE 0: bf16 out, * (0.125*log2e) (qp) | MODE 1: kv split K + V^T-permuted | MODE 2: f32+bias
template<int MODE, int BN>
__device__ __forceinline__ void gemm_body(bf16* lA, bf16* lB,
    const bf16* __restrict__ A, const bf16* __restrict__ Bm,
    void* __restrict__ out0, void* __restrict__ out1,
    const float* __restrict__ bias, int M, int N, int bid) {
  constexpr int K = 1024;
  constexpr int MI = (BN == 128) ? 4 : 2;
  constexpr int NBL = (BN == 128) ? 4 : 2;
  const int nbn = N / BN;
  const int bm = bid / nbn, bn = bid - bm * nbn;
  const int m0 = bm << 7, n0 = bn * BN;
  const int tid = threadIdx.x;
  const int lane = tid & 63, wid = tid >> 6;
  const int rowb = (BN == 128) ? ((wid >> 1) * 64) : (wid * 32);
  const int colb = (BN == 128) ? ((wid & 1) * 64) : 0;
  const int l15 = lane & 15, lg = lane >> 4;

  f32x4 acc[MI][4] = {};

  const bf16* gA[4]; const bf16* gB[NBL];
#pragma unroll
  for (int u = 0; u < 4; ++u) {
    int s = tid + u * 256;
    int row = s >> 3, c8 = (s & 7) ^ (row & 7);
    gA[u] = A + (size_t)(m0 + row) * K + c8 * 8;
  }
#pragma unroll
  for (int u = 0; u < NBL; ++u) {
    int s = tid + u * 256;
    int row = s >> 3, c8 = (s & 7) ^ (row & 7);
    gB[u] = Bm + (size_t)(n0 + row) * K + c8 * 8;
  }

  const int sw = l15 & 7;

  for (int k0 = 0; k0 < K; k0 += 64) {
#pragma unroll
    for (int u = 0; u < 4; ++u)
      __builtin_amdgcn_global_load_lds((gptr_t)(gA[u] + k0), (sptr_t)(lA + (tid + u * 256) * 8), 16, 0, 0);
#pragma unroll
    for (int u = 0; u < NBL; ++u)
      __builtin_amdgcn_global_load_lds((gptr_t)(gB[u] + k0), (sptr_t)(lB + (tid + u * 256) * 8), 16, 0, 0);
    __syncthreads();
#pragma unroll
    for (int ks2 = 0; ks2 < 2; ++ks2) {
      const int soff = ((ks2 * 4 + lg) ^ sw) * 8;
      bf16x8 af[MI], bfr[4];
#pragma unroll
      for (int i = 0; i < MI; ++i)
        af[i]  = *reinterpret_cast<const bf16x8*>(lA + (rowb + i * 16 + l15) * 64 + soff);
#pragma unroll
      for (int j = 0; j < 4; ++j)
        bfr[j] = *reinterpret_cast<const bf16x8*>(lB + (colb + j * 16 + l15) * 64 + soff);
#pragma unroll
      for (int i = 0; i < MI; ++i)
#pragma unroll
        for (int j = 0; j < 4; ++j)
          acc[i][j] = __builtin_amdgcn_mfma_f32_16x16x32_bf16(af[i], bfr[j], acc[i][j], 0, 0, 0);
    }
    __syncthreads();
  }

  const int mB = m0 + rowb + lg * 4;
  const int nB = n0 + colb + l15;
  if constexpr (MODE == 0) {
    bf16* o = reinterpret_cast<bf16*>(out0);
    constexpr float SC = 0.125f * 1.44269504089f;  // DH^-0.5 * log2(e)
#pragma unroll
    for (int i = 0; i < MI; ++i)
#pragma unroll
      for (int j = 0; j < 4; ++j)
#pragma unroll
        for (int r = 0; r < 4; ++r)
          o[(size_t)(mB + i * 16 + r) * N + nB + j * 16] = (bf16)(acc[i][j][r] * SC);
  } else if constexpr (MODE == 2) {
    float* o = reinterpret_cast<float*>(out0);
#pragma unroll
    for (int j = 0; j < 4; ++j) {
      float bj = bias[nB + j * 16];
#pragma unroll
      for (int i = 0; i < MI; ++i)
#pragma unroll
        for (int r = 0; r < 4; ++r)
          o[(size_t)(mB + i * 16 + r) * N + nB + j * 16] = acc[i][j][r] + bj;
    }
  } else {
    if (n0 < 1024) {  // K part: (B,NKV,DI)
      bf16* o = reinterpret_cast<bf16*>(out0);
#pragma unroll
      for (int i = 0; i < MI; ++i)
#pragma unroll
        for (int j = 0; j < 4; ++j)
#pragma unroll
          for (int r = 0; r < 4; ++r)
            o[(size_t)(mB + i * 16 + r) * 1024 + nB + j * 16] = (bf16)acc[i][j][r];
    } else {          // V part: transposed (B,DI,NKV) with in-64 column swizzle
      bf16* o = reinterpret_cast<bf16*>(out1);
#pragma unroll
      for (int i = 0; i < MI; ++i) {
        int m = mB + i * 16;
        int bb_ = m >> 11, kv = m & 2047;
        int u = kv & 63;
        int c = (u & 32) | ((u & 12) << 1) | ((u & 16) >> 2) | (u & 3);
        int col = (kv & ~63) | c;
#pragma unroll
        for (int j = 0; j < 4; ++j) {
          int nv = nB + j * 16 - 1024;
          bf16x4 pk;
          pk[0] = (bf16)acc[i][j][0]; pk[1] = (bf16)acc[i][j][1];
          pk[2] = (bf16)acc[i][j][2]; pk[3] = (bf16)acc[i][j][3];
          *reinterpret_cast<bf16x4*>(o + ((size_t)(bb_ << 10) + nv) * 2048 + col) = pk;
        }
      }
    }
  }
}

template<int MODE, int BN>
__global__ __launch_bounds__(256) void gemm_bt(const bf16* __restrict__ A,
    const bf16* __restrict__ Bm, void* __restrict__ out0, void* __restrict__ out1,
    const float* __restrict__ bias, int M, int N) {
  __shared__ bf16 lA[128 * 64];
  __shared__ bf16 lB[BN * 64];
  const int cpx = gridDim.x >> 3;
  const int bid = (blockIdx.x & 7) * cpx + (blockIdx.x >> 3);
  gemm_body<MODE, BN>(lA, lB, A, Bm, out0, out1, bias, M, N, bid);
}

// Merged qp + kv GEMM: blocks [0,1024) = kv (MODE 1), [1024,1280) = qp (MODE 0, BN=128).
__global__ __launch_bounds__(256) void gemm_fused(
    const bf16* __restrict__ qn, const bf16* __restrict__ Wq, void* __restrict__ qpb,
    const bf16* __restrict__ cn, const bf16* __restrict__ Wkv,
    void* __restrict__ kbuf, void* __restrict__ vT) {
  __shared__ bf16 lA[128 * 64];
  __shared__ bf16 lB[128 * 64];
  if (blockIdx.x < 1024) {
    int rb = blockIdx.x;
    int bid = (rb & 7) * 128 + (rb >> 3);
    gemm_body<1, 128>(lA, lB, cn, Wkv, kbuf, vT, nullptr, 8192, 2048, bid);
  } else {
    int rb = blockIdx.x - 1024;
    int bid = (rb & 7) * 32 + (rb >> 3);
    gemm_body<0, 128>(lA, lB, qn, Wq, qpb, nullptr, nullptr, 4096, 1024, bid);
  }
}

// ---------------- Flash attention v7 (proven 56 us): KVBLK=128, 8 waves x 16q ----------------
// S^T = mfma(K, Q): lane holds S[q = lane&15][kv = ni*16 + lg*4 + r] (exp2-domain logits).
// K/V tiles staged to LDS in fragment-slot-major order (16B slot = frag*64 + lane);
// stage source addresses carry the inverse permutation (pre-swizzled-source, linear LDS).
// 128-kv tile = two 64-groups; the V in-64 column swizzle applies per group.
__global__ __launch_bounds__(512, 4) void attn_kernel(const bf16* __restrict__ qp,
    const bf16* __restrict__ kk, const bf16* __restrict__ vTp, bf16* __restrict__ out) {
  __shared__ bf16 smem[32768];   // [K dbuf 2x8192][V dbuf 2x8192]  (64 KB)
  // XCD-aware bijective remap: the 8 q-tiles of one (b,h) land on one XCD
  const int pos = blockIdx.x;
  const int idx = pos >> 3;
  const int bh = ((idx >> 3) << 3) | (pos & 7);
  const int qt = idx & 7;
  const int b = bh >> 4, h = bh & 15;
  const int tid = threadIdx.x;              // 0..511
  const int lane = tid & 63, w = tid >> 6;  // 8 waves
  const int l15 = lane & 15, lg = lane >> 4;

  const bf16* Qb = qp + (size_t)(b * NQ + qt * 128 + w * 16) * DI + h * DH;
  const bf16* Kb = kk + (size_t)b * NKV * DI + h * DH;
  const bf16* Vb = vTp + (size_t)(b * DI + h * DH) * NKV;

  // K slots (1024 x 16B): bits [9:7]=ni, [6]=ks, [5:4]=lg, [3:0]=l15
  // V slots (1024 x 16B): bits [9:8]=dt, [7:6]=k2, [5:4]=lg, [3:0]=l15
  const int sA = tid, sB = tid + 512;
  const int rKA = ((sA >> 7) << 4) | (sA & 15), cKA = ((sA >> 4) & 7) * 8;
  const int rKB = ((sB >> 7) << 4) | (sB & 15), cKB = ((sB >> 4) & 7) * 8;
  const int rVA = ((sA >> 8) << 4) | (sA & 15), cVA = ((sA >> 6) & 3) * 32 + ((sA >> 4) & 3) * 8;
  const int rVB = ((sB >> 8) << 4) | (sB & 15), cVB = ((sB >> 6) & 3) * 32 + ((sB >> 4) & 3) * 8;
  const bf16* pKA = Kb + (size_t)rKA * DI + cKA;   // + kv0*DI per tile
  const bf16* pKB = Kb + (size_t)rKB * DI + cKB;
  const bf16* pVA = Vb + (size_t)rVA * NKV + cVA;  // + kv0 per tile
  const bf16* pVB = Vb + (size_t)rVB * NKV + cVB;

#define STAGE_KV(bufsel, kv)                                                                        \
  do {                                                                                              \
    __builtin_amdgcn_global_load_lds((gptr_t)(pKA + (size_t)(kv) * DI),                             \
                                     (sptr_t)(smem + (bufsel) * 8192 + sA * 8), 16, 0, 0);          \
    __builtin_amdgcn_global_load_lds((gptr_t)(pKB + (size_t)(kv) * DI),                             \
                                     (sptr_t)(smem + (bufsel) * 8192 + sB * 8), 16, 0, 0);          \
    __builtin_amdgcn_global_load_lds((gptr_t)(pVA + (kv)),                                          \
                                     (sptr_t)(smem + 16384 + (bufsel) * 8192 + sA * 8), 16, 0, 0);  \
    __builtin_amdgcn_global_load_lds((gptr_t)(pVB + (kv)),                                          \
                                     (sptr_t)(smem + 16384 + (bufsel) * 8192 + sB * 8), 16, 0, 0);  \
  } while (0)

  bf16x8 qf[2];
#pragma unroll
  for (int ks = 0; ks < 2; ++ks)
    qf[ks] = *reinterpret_cast<const bf16x8*>(Qb + (size_t)l15 * DI + ks * 32 + lg * 8);

  f32x4 o[4] = {};
  float mrun = -1e30f;
  float lpart = 0.0f;    // per-lane partial row-sum (reduced across lg at epilogue)

  STAGE_KV(0, 0);
  __syncthreads();
  int cur = 0;

  for (int kv0 = 0; kv0 < NKV; kv0 += 128) {
    const bool notlast = (kv0 + 128 < NKV);
    if (notlast) STAGE_KV(cur ^ 1, kv0 + 128);   // issue early; drained by tile-end barrier

    const bf16* Kl = smem + cur * 8192;
    const bf16* Vl = smem + 16384 + cur * 8192;

    // ---- QK^T (swapped operands), two 64-kv groups ----
    f32x4 s[8] = {};
#pragma unroll
    for (int h2 = 0; h2 < 2; ++h2) {
      bf16x8 kf[4][2];
#pragma unroll
      for (int ni = 0; ni < 4; ++ni)
#pragma unroll
        for (int ks = 0; ks < 2; ++ks)
          kf[ni][ks] = *reinterpret_cast<const bf16x8*>(Kl + (((h2 * 4 + ni) * 2 + ks) * 64 + lane) * 8);
      __builtin_amdgcn_s_setprio(1);
#pragma unroll
      for (int ni = 0; ni < 4; ++ni)
#pragma unroll
        for (int ks = 0; ks < 2; ++ks)
          s[h2 * 4 + ni] = __builtin_amdgcn_mfma_f32_16x16x32_bf16(kf[ni][ks], qf[ks], s[h2 * 4 + ni], 0, 0, 0);
      __builtin_amdgcn_s_setprio(0);
    }

    // ---- softmax (per q = l15; exp2 domain) ----
    f32x4 mv = s[0];
#pragma unroll
    for (int i = 1; i < 8; ++i) {
      mv[0] = fmaxf(mv[0], s[i][0]); mv[1] = fmaxf(mv[1], s[i][1]);
      mv[2] = fmaxf(mv[2], s[i][2]); mv[3] = fmaxf(mv[3], s[i][3]);
    }
    float pm = fmaxf(fmaxf(mv[0], mv[1]), fmaxf(mv[2], mv[3]));
    pm = fmaxf(pm, __shfl_xor(pm, 16));
    pm = fmaxf(pm, __shfl_xor(pm, 32));

    const bool noresc = __all(pm <= mrun);   // exact: corr == 1 when no new max
    const float mnew = noresc ? mrun : fmaxf(mrun, pm);

    f32x4 sv = {};
#pragma unroll
    for (int i = 0; i < 8; ++i) {
#pragma unroll
      for (int r = 0; r < 4; ++r) {
        s[i][r] = __builtin_amdgcn_exp2f(s[i][r] - mnew);
        sv[r] += s[i][r];
      }
    }
    const float rs_local = (sv[0] + sv[1]) + (sv[2] + sv[3]);

    if (noresc) {
      lpart += rs_local;
    } else {
      float corr = __builtin_amdgcn_exp2f(mrun - mnew);
      lpart = lpart * corr + rs_local;
      mrun = mnew;
      float c0 = __shfl(corr, lg * 4 + 0);
      float c1 = __shfl(corr, lg * 4 + 1);
      float c2 = __shfl(corr, lg * 4 + 2);
      float c3 = __shfl(corr, lg * 4 + 3);
#pragma unroll
      for (int dt = 0; dt < 4; ++dt) {
        o[dt][0] *= c0; o[dt][1] *= c1; o[dt][2] *= c2; o[dt][3] *= c3;
      }
    }

    // ---- pack P (register-only): pa[k2], k2 = h2*2 + k2' ----
    bf16x8 pa[4];
#pragma unroll
    for (int h2 = 0; h2 < 2; ++h2)
#pragma unroll
      for (int k2p = 0; k2p < 2; ++k2p)
#pragma unroll
        for (int jj = 0; jj < 4; ++jj) {
          pa[h2 * 2 + k2p][jj]     = (bf16)s[h2 * 4 + k2p * 2 + 0][jj];
          pa[h2 * 2 + k2p][4 + jj] = (bf16)s[h2 * 4 + k2p * 2 + 1][jj];
        }

    // ---- PV: 16 MFMA, V fragments streamed per k2 ----
    __builtin_amdgcn_s_setprio(1);
#pragma unroll
    for (int k2 = 0; k2 < 4; ++k2) {
      bf16x8 vf[4];
#pragma unroll
      for (int dt = 0; dt < 4; ++dt)
        vf[dt] = *reinterpret_cast<const bf16x8*>(Vl + ((dt * 4 + k2) * 64 + lane) * 8);
#pragma unroll
      for (int dt = 0; dt < 4; ++dt)
        o[dt] = __builtin_amdgcn_mfma_f32_16x16x32_bf16(pa[k2], vf[dt], o[dt], 0, 0, 0);
    }
    __builtin_amdgcn_s_setprio(0);

    if (notlast) __syncthreads();   // drains this tile's prefetch (already overlapped)
    cur ^= 1;
  }
#undef STAGE_KV

  // epilogue: reduce per-lane partials, normalize, store
  float lsum = lpart;
  lsum += __shfl_xor(lsum, 16);
  lsum += __shfl_xor(lsum, 32);
  const float inv = 1.0f / lsum;               // valid for q = l15
  const float iv0 = __shfl(inv, lg * 4 + 0);
  const float iv1 = __shfl(inv, lg * 4 + 1);
  const float iv2 = __shfl(inv, lg * 4 + 2);
  const float iv3 = __shfl(inv, lg * 4 + 3);

  bf16* Ob = out + (size_t)(b * NQ + qt * 128 + w * 16) * DI + h * DH;
#pragma unroll
  for (int dt = 0; dt < 4; ++dt) {
    Ob[(size_t)(lg * 4 + 0) * DI + dt * 16 + l15] = (bf16)(o[dt][0] * iv0);
    Ob[(size_t)(lg * 4 + 1) * DI + dt * 16 + l15] = (bf16)(o[dt][1] * iv1);
    Ob[(size_t)(lg * 4 + 2) * DI + dt * 16 + l15] = (bf16)(o[dt][2] * iv2);
    Ob[(size_t)(lg * 4 + 3) * DI + dt * 16 + l15] = (bf16)(o[dt][3] * iv3);
  }
}

// ---------------- launch ----------------
extern "C" void kernel_launch(void* const* d_in, const int* in_sizes, int n_in,
                              void* d_out, int out_size, void* d_ws, size_t ws_size,
                              hipStream_t stream) {
  const float* q     = (const float*)d_in[0];
  const float* ctx   = (const float*)d_in[1];
  const float* Wq    = (const float*)d_in[2];
  const float* Wkv   = (const float*)d_in[3];
  const float* Wproj = (const float*)d_in[4];
  const float* bproj = (const float*)d_in[5];
  const float* qg    = (const float*)d_in[6];
  const float* qb    = (const float*)d_in[7];
  const float* cg    = (const float*)d_in[8];
  const float* cb    = (const float*)d_in[9];

  char* ws = (char*)d_ws;
  bf16* qn    = (bf16*)(ws);                       // 8 MB  (4096x1024)
  bf16* cn    = (bf16*)(ws + ( 8ull << 20));       // 16 MB (8192x1024)
  bf16* Wq_b  = (bf16*)(ws + (24ull << 20));       // 2 MB
  bf16* Wkv_b = (bf16*)(ws + (26ull << 20));       // 4 MB
  bf16* Wp_b  = (bf16*)(ws + (30ull << 20));       // 2 MB
  bf16* qpb   = (bf16*)(ws + (32ull << 20));       // 8 MB  (4096x1024)
  bf16* kbuf  = (bf16*)(ws + (40ull << 20));       // 16 MB (B,NKV,DI)
  bf16* vT    = (bf16*)(ws + (56ull << 20));       // 16 MB (B,DI,NKV) swizzled
  bf16* aout  = (bf16*)(ws + (72ull << 20));       // 8 MB  (4096x1024)

  cvt_all<<<4096, 256, 0, stream>>>(Wq, Wkv, Wproj, Wq_b, Wkv_b, Wp_b);
  ln_kernel<<<12288, 256, 0, stream>>>(q, ctx, qg, qb, cg, cb, qn, cn);

  gemm_fused<<<1280, 256, 0, stream>>>(qn, Wq_b, qpb, cn, Wkv_b, kbuf, vT);

  attn_kernel<<<512, 512, 0, stream>>>(qpb, kbuf, vT, aout);

  gemm_bt<2, 64><<<512, 256, 0, stream>>>(aout, Wp_b, d_out, nullptr, bproj, 4096, 1024);
}